// Round 11
// baseline (245.713 us; speedup 1.0000x reference)
//
#include <hip/hip_runtime.h>

typedef unsigned short u16;
typedef __attribute__((ext_vector_type(8))) short bf16x8;
typedef __attribute__((ext_vector_type(4))) float f32x4;

// round-to-nearest (ties away): 2 VALU ops
__device__ __forceinline__ u16 f2bf(float f) {
    return (u16)((__float_as_uint(f) + 0x8000u) >> 16);
}

#define N_NODES 2048
#define D_EMB 64
#define P_DIM 32
#define NS_STOPS 512
#define IN_LEN 4131   // 32 + 2048 + 2048 + 3
#define KGEMM 4160    // 2048 es + 2048 dist + 32 pref + 32 zero-pad
#define NKT 65        // K-tiles of 64

// 16B-chunk XOR swizzle within a tile row (8 chunks of 8 shorts)
#define SWZ(row, c) ((((row) * 8) + ((c) ^ ((row) & 7))) * 8)

__device__ __forceinline__ void gload16(const u16* g, u16* l) {
    __builtin_amdgcn_global_load_lds((const __attribute__((address_space(1))) void*)g,
                                     (__attribute__((address_space(3))) void*)l, 16, 0, 0);
}

// ---------------- zero d_out (atomic accumulation target) ----------------
__global__ void k_zero(float* __restrict__ out) {
    int idx = blockIdx.x * 256 + threadIdx.x;
    ((f32x4*)out)[idx] = (f32x4){0.f, 0.f, 0.f, 0.f};
}

// ---------------- keep mask + compact list (single block) ----------------
__global__ __launch_bounds__(1024) void k_keep(const int* __restrict__ stops, int* __restrict__ keep,
                                               int* __restrict__ klist, int* __restrict__ knum) {
    __shared__ int s[NS_STOPS];
    __shared__ int cnt;
    int t = threadIdx.x;
    if (t < NS_STOPS) s[t] = stops[t];
    if (t == 0) cnt = 0;
    __syncthreads();
    for (int n = t; n < N_NODES; n += 1024) {
        int f = 0;
        for (int u = 0; u < NS_STOPS; ++u) f |= (s[u] == n);
        keep[n] = f;
        if (f) { int p = atomicAdd(&cnt, 1); klist[p] = n; }
    }
    __syncthreads();
    if (t == 0) *knum = cnt;
}

// ---------------- row-normalized embeddings (fp32) ----------------
__global__ void k_xn(const float* __restrict__ emb, float* __restrict__ xn) {
    int t = threadIdx.x;
    int row = blockIdx.x * 4 + (t >> 6);
    int d = t & 63;
    float v = emb[row * D_EMB + d];
    float s = v * v;
    #pragma unroll
    for (int off = 32; off; off >>= 1) s += __shfl_xor(s, off, 64);
    float nm = fmaxf(sqrtf(s), 1e-8f);
    xn[row * D_EMB + d] = v / nm;
}

// ---------------- fused: cosine graph + mean agg + pref + a,b ----------------
__global__ __launch_bounds__(256) void k_aggpref(const float* __restrict__ xn, const float* __restrict__ emb,
                                                 const int* __restrict__ keep, const int* __restrict__ klist,
                                                 const int* __restrict__ knum,
                                                 const float* __restrict__ lin_l_w, const float* __restrict__ lin_l_b,
                                                 const float* __restrict__ lin_r_w, const float* __restrict__ edge_w,
                                                 float* __restrict__ pref, float* __restrict__ av, float* __restrict__ bv) {
    int i = blockIdx.x, t = threadIdx.x;
    __shared__ float xi[D_EMB];
    __shared__ float embL[D_EMB];
    __shared__ float aggL[D_EMB];
    __shared__ int degL;
    int ki = keep[i];            // block-uniform
    if (t < D_EMB) { xi[t] = xn[i * D_EMB + t]; embL[t] = emb[i * D_EMB + t]; aggL[t] = 0.f; }
    if (t == 0) degL = 0;
    __syncthreads();
    if (ki) {
        int nk = knum[0];
        const f32x4* xiv = (const f32x4*)xi;
        for (int u = t; u < nk; u += 256) {
            int j = klist[u];
            if (j == i) continue;
            const f32x4* xj = (const f32x4*)&xn[j * D_EMB];
            f32x4 dv = {0.f, 0.f, 0.f, 0.f};
            #pragma unroll
            for (int d = 0; d < 16; ++d) dv += xiv[d] * xj[d];
            float dot = dv[0] + dv[1] + dv[2] + dv[3];
            if (dot > 0.5f) {
                atomicAdd(&degL, 1);
                #pragma unroll
                for (int d = 0; d < D_EMB; ++d) atomicAdd(&aggL[d], emb[j * D_EMB + d]);
            }
        }
    }
    __syncthreads();
    if (t < D_EMB) {
        float deg = fmaxf((float)degL, 1.0f);
        aggL[t] = ki ? (aggL[t] / deg) : 0.f;    // aggL now holds aggd row
    }
    __syncthreads();
    if (t < P_DIM) {   // wave 0
        float s = lin_l_b[t];
        const float* wl = &lin_l_w[t * D_EMB];
        const float* wr = &lin_r_w[t * D_EMB];
        #pragma unroll
        for (int d = 0; d < D_EMB; ++d) s += aggL[d] * wl[d] + embL[d] * wr[d];
        pref[i * P_DIM + t] = s;
        float a = s * edge_w[t];
        float b = s * edge_w[P_DIM + t];
        #pragma unroll
        for (int off = 16; off; off >>= 1) { a += __shfl_xor(a, off, 64); b += __shfl_xor(b, off, 64); }
        if (t == 0) { av[i] = a; bv[i] = b; }
    }
}

// ---------------- pack B tiled+pre-swizzled + cvec/w3 (fused) ----------------
// Bp[nt][kt][r(128)][c^(r&7)] ; j row = nt*128+r
__global__ void k_packB_cvec(const float* __restrict__ comb_w, const float* __restrict__ comb_b,
                             const int* __restrict__ wk_p, const int* __restrict__ vh_p,
                             u16* __restrict__ Bp, float* __restrict__ cvec, float* __restrict__ w3) {
    int j = blockIdx.x, t = threadIdx.x;
    int nt = j >> 7, r = j & 127;
    const float* cw = comb_w + (size_t)j * IN_LEN;
    for (int q = t; q < 520; q += 256) {
        int kt = q >> 3, c = q & 7;
        int k0 = q * 8;
        bf16x8 v;
        if (k0 < 4096) {
            float tmp[8];
            __builtin_memcpy(tmp, cw + 32 + k0, 32);
            #pragma unroll
            for (int e = 0; e < 8; ++e) v[e] = (short)f2bf(tmp[e]);
        } else if (k0 < 4128) {
            float tmp[8];
            __builtin_memcpy(tmp, cw + (k0 - 4096), 32);
            #pragma unroll
            for (int e = 0; e < 8; ++e) v[e] = (short)f2bf(tmp[e]);
        } else {
            #pragma unroll
            for (int e = 0; e < 8; ++e) v[e] = 0;
        }
        size_t off = (((size_t)nt * NKT + kt) * 128 + r) * 64 + (size_t)((c ^ (r & 7)) * 8);
        *(bf16x8*)&Bp[off] = v;
    }
    if (t == 0) {
        float wk = (float)wk_p[0], vh = (float)vh_p[0];
        cvec[j] = wk * cw[4128] + vh * cw[4129] + comb_b[j];
        w3[j] = cw[4130];
    }
}

// ---------------- pack A tiled+pre-swizzled (128-row tiles) ----------------
// Ap[mt][kt][r(128)][c^(r&7)] ; row = mt*128+r
__global__ void k_pack_At(const float* __restrict__ dist, const float* __restrict__ pref,
                          const float* __restrict__ av, const float* __restrict__ bv,
                          const float* __restrict__ edge_b, u16* __restrict__ Ap) {
    int row = blockIdx.x, t = threadIdx.x;
    int mt = row >> 7, r = row & 127;
    float ab = av[row] + edge_b[0];
    const float* drow = dist + (size_t)row * 2048;
    const float* prow = pref + (size_t)row * P_DIM;
    for (int q = t; q < 520; q += 256) {
        int kt = q >> 3, c = q & 7;
        int k0 = q * 8;
        bf16x8 v;
        #pragma unroll
        for (int e = 0; e < 8; ++e) {
            int k = k0 + e;
            float val;
            if (k < 2048) { val = ab + bv[k]; val = (val >= 0.f) ? val : 0.01f * val; }
            else if (k < 4096) val = drow[k - 2048];
            else if (k < 4128) val = prow[k - 4096];
            else val = 0.f;
            v[e] = (short)f2bf(val);
        }
        size_t off = (((size_t)mt * NKT + kt) * 128 + r) * 64 + (size_t)((c ^ (r & 7)) * 8);
        *(bf16x8*)&Ap[off] = v;
    }
}

// ---------------- split-K GEMM: 128x128 tile, K split in 2, atomic accumulate ----------------
__global__ __launch_bounds__(256) void k_gemm_s(const u16* __restrict__ Ap, const u16* __restrict__ Bp,
                                                float* __restrict__ Cout) {
    __shared__ __attribute__((aligned(16))) short As[128 * 64];   // 16 KB
    __shared__ __attribute__((aligned(16))) short Bs[128 * 64];   // 16 KB
    int t = threadIdx.x;
    int mt = blockIdx.y, nt = blockIdx.x, sp = blockIdx.z;
    int tileM = mt * 128, tileN = nt * 128;
    int kt0 = sp ? 32 : 0;
    int ktN = sp ? NKT : 32;
    int lane = t & 63;
    int wid = t >> 6;
    int waveM = wid & 1, waveN = wid >> 1;
    int l16 = lane & 15, quad = lane >> 4;

    f32x4 acc[4][4];
    #pragma unroll
    for (int a_ = 0; a_ < 4; ++a_)
        #pragma unroll
        for (int b_ = 0; b_ < 4; ++b_) acc[a_][b_] = (f32x4){0.f, 0.f, 0.f, 0.f};

    const u16* ga = Ap + ((size_t)mt * NKT + kt0) * 8192 + t * 8;
    const u16* gb = Bp + ((size_t)nt * NKT + kt0) * 8192 + t * 8;
    u16* asDst = (u16*)As + t * 8;
    u16* bsDst = (u16*)Bs + t * 8;

    for (int kt = kt0; kt < ktN; ++kt) {
        __syncthreads();
        #pragma unroll
        for (int u = 0; u < 4; ++u) {
            gload16(ga + u * 2048, asDst + u * 2048);
            gload16(gb + u * 2048, bsDst + u * 2048);
        }
        ga += 8192; gb += 8192;
        __syncthreads();   // vmcnt(0) drain + barrier
        #pragma unroll
        for (int kk = 0; kk < 64; kk += 32) {
            int cbase = kk >> 3;
            bf16x8 af[4], bfr[4];
            #pragma unroll
            for (int mi = 0; mi < 4; ++mi) {
                int row = waveM * 64 + mi * 16 + l16;
                af[mi] = *(const bf16x8*)&As[SWZ(row, cbase + quad)];
            }
            #pragma unroll
            for (int ni = 0; ni < 4; ++ni) {
                int row = waveN * 64 + ni * 16 + l16;
                bfr[ni] = *(const bf16x8*)&Bs[SWZ(row, cbase + quad)];
            }
            #pragma unroll
            for (int mi = 0; mi < 4; ++mi)
                #pragma unroll
                for (int ni = 0; ni < 4; ++ni)
                    acc[mi][ni] = __builtin_amdgcn_mfma_f32_16x16x32_bf16(af[mi], bfr[ni], acc[mi][ni], 0, 0, 0);
        }
    }
    #pragma unroll
    for (int mi = 0; mi < 4; ++mi)
        #pragma unroll
        for (int ni = 0; ni < 4; ++ni) {
            int row = tileM + waveM * 64 + mi * 16 + quad * 4;
            int col = tileN + waveN * 64 + ni * 16 + l16;
            float* cp = Cout + (size_t)row * N_NODES + col;
            #pragma unroll
            for (int rr = 0; rr < 4; ++rr)
                unsafeAtomicAdd(cp + (size_t)rr * N_NODES, acc[mi][ni][rr]);
        }
}

// ---------------- epilogue: + cvec + keep_i*w3, log-softmax (f32x4, in place) ----------------
__global__ __launch_bounds__(256) void k_epi(const float* __restrict__ cvec, const float* __restrict__ w3,
                                             const int* __restrict__ keep, float* __restrict__ out) {
    int i = blockIdx.x, t = threadIdx.x;
    __shared__ float redmax[4], redsum[4];
    float ki = keep[i] ? 1.f : 0.f;
    f32x4* orow = (f32x4*)(out + (size_t)i * N_NODES);
    const f32x4* cv = (const f32x4*)cvec;
    const f32x4* wv = (const f32x4*)w3;
    f32x4 v0 = orow[t] + cv[t] + ki * wv[t];
    f32x4 v1 = orow[t + 256] + cv[t + 256] + ki * wv[t + 256];
    float vmax = fmaxf(fmaxf(fmaxf(v0[0], v0[1]), fmaxf(v0[2], v0[3])),
                       fmaxf(fmaxf(v1[0], v1[1]), fmaxf(v1[2], v1[3])));
    #pragma unroll
    for (int off = 32; off; off >>= 1) vmax = fmaxf(vmax, __shfl_xor(vmax, off, 64));
    if ((t & 63) == 0) redmax[t >> 6] = vmax;
    __syncthreads();
    vmax = fmaxf(fmaxf(redmax[0], redmax[1]), fmaxf(redmax[2], redmax[3]));
    float se = 0.f;
    #pragma unroll
    for (int e = 0; e < 4; ++e) se += expf(v0[e] - vmax) + expf(v1[e] - vmax);
    #pragma unroll
    for (int off = 32; off; off >>= 1) se += __shfl_xor(se, off, 64);
    if ((t & 63) == 0) redsum[t >> 6] = se;
    __syncthreads();
    se = redsum[0] + redsum[1] + redsum[2] + redsum[3];
    float lz = vmax + logf(se);
    orow[t] = v0 - lz;
    orow[t + 256] = v1 - lz;
}

extern "C" void kernel_launch(void* const* d_in, const int* in_sizes, int n_in,
                              void* d_out, int out_size, void* d_ws, size_t ws_size,
                              hipStream_t stream) {
    const float* dist    = (const float*)d_in[0];
    const float* emb     = (const float*)d_in[1];
    const float* lin_l_w = (const float*)d_in[2];
    const float* lin_l_b = (const float*)d_in[3];
    const float* lin_r_w = (const float*)d_in[4];
    const float* edge_w  = (const float*)d_in[5];
    const float* edge_b  = (const float*)d_in[6];
    const float* comb_w  = (const float*)d_in[7];
    const float* comb_b  = (const float*)d_in[8];
    const int* stops     = (const int*)d_in[9];
    const int* wk        = (const int*)d_in[10];
    const int* vh        = (const int*)d_in[11];

    // ws layout (<= 34.93 MB, confirmed budget >= 35.43 MB)
    char* ws = (char*)d_ws;
    float* xn    = (float*)(ws + 0);          // 524288
    int*   keep  = (int*)(ws + 524288);       // 8192
    float* pref  = (float*)(ws + 532480);     // 262144
    float* av    = (float*)(ws + 794624);     // 8192
    float* bv    = (float*)(ws + 802816);     // 8192
    float* cvec  = (float*)(ws + 811008);     // 8192
    float* w3    = (float*)(ws + 819200);     // 8192
    int*   klist = (int*)(ws + 827392);       // 8192
    int*   knum  = (int*)(ws + 835584);       // 64
    u16*   Ap    = (u16*)(ws + 843776);       // 17039360 -> 17883136
    u16*   Bp    = (u16*)(ws + 17883136);     // 17039360 -> 34922496
    float* out   = (float*)d_out;             // f32 [2048,2048]

    hipLaunchKernelGGL(k_zero,       dim3(4096), dim3(256),  0, stream, out);
    hipLaunchKernelGGL(k_keep,       dim3(1),    dim3(1024), 0, stream, stops, keep, klist, knum);
    hipLaunchKernelGGL(k_xn,         dim3(512),  dim3(256),  0, stream, emb, xn);
    hipLaunchKernelGGL(k_aggpref,    dim3(2048), dim3(256),  0, stream, xn, emb, keep, klist, knum,
                       lin_l_w, lin_l_b, lin_r_w, edge_w, pref, av, bv);
    hipLaunchKernelGGL(k_packB_cvec, dim3(2048), dim3(256),  0, stream, comb_w, comb_b, wk, vh, Bp, cvec, w3);
    hipLaunchKernelGGL(k_pack_At,    dim3(2048), dim3(256),  0, stream, dist, pref, av, bv, edge_b, Ap);
    hipLaunchKernelGGL(k_gemm_s,     dim3(16, 16, 2), dim3(256), 0, stream, Ap, Bp, out);
    hipLaunchKernelGGL(k_epi,        dim3(2048), dim3(256),  0, stream, cvec, w3, keep, out);
}

// Round 12
// 196.579 us; speedup vs baseline: 1.2499x; 1.2499x over previous
//
#include <hip/hip_runtime.h>

typedef unsigned short u16;
typedef __attribute__((ext_vector_type(8))) short bf16x8;
typedef __attribute__((ext_vector_type(4))) float f32x4;

// round-to-nearest (ties away): 2 VALU ops
__device__ __forceinline__ u16 f2bf(float f) {
    return (u16)((__float_as_uint(f) + 0x8000u) >> 16);
}

#define N_NODES 2048
#define D_EMB 64
#define P_DIM 32
#define NS_STOPS 512
#define IN_LEN 4131   // 32 + 2048 + 2048 + 3
#define NKT 65        // K-tiles of 64 (2048 es + 2048 dist + 32 pref + 32 pad)

// 16B-chunk XOR swizzle within a tile row (8 chunks of 8 shorts)
#define SWZ(row, c) ((((row) * 8) + ((c) ^ ((row) & 7))) * 8)

__device__ __forceinline__ void gload16(const u16* g, u16* l) {
    __builtin_amdgcn_global_load_lds((const __attribute__((address_space(1))) void*)g,
                                     (__attribute__((address_space(3))) void*)l, 16, 0, 0);
}

// ---------------- fused prep: blocks 0..511 = xn ; block 512 = keep mask + compact list ----------------
__global__ __launch_bounds__(256) void k_prep(const float* __restrict__ emb, const int* __restrict__ stops,
                                              float* __restrict__ xn, int* __restrict__ keep,
                                              int* __restrict__ klist, int* __restrict__ knum) {
    int t = threadIdx.x;
    if (blockIdx.x < 512) {
        int row = blockIdx.x * 4 + (t >> 6);
        int d = t & 63;
        float v = emb[row * D_EMB + d];
        float s = v * v;
        #pragma unroll
        for (int off = 32; off; off >>= 1) s += __shfl_xor(s, off, 64);
        float nm = fmaxf(sqrtf(s), 1e-8f);
        xn[row * D_EMB + d] = v / nm;
    } else {
        __shared__ int cnt;
        if (t == 0) cnt = 0;
        for (int n = t; n < N_NODES; n += 256) keep[n] = 0;
        __syncthreads();
        for (int u = t; u < NS_STOPS; u += 256) keep[stops[u]] = 1;   // races benign
        __syncthreads();
        for (int n = t; n < N_NODES; n += 256)
            if (keep[n]) { int p = atomicAdd(&cnt, 1); klist[p] = n; }
        __syncthreads();
        if (t == 0) *knum = cnt;
    }
}

// ---------------- fused: cosine graph + mean agg + pref + a,b ----------------
__global__ __launch_bounds__(256) void k_aggpref(const float* __restrict__ xn, const float* __restrict__ emb,
                                                 const int* __restrict__ keep, const int* __restrict__ klist,
                                                 const int* __restrict__ knum,
                                                 const float* __restrict__ lin_l_w, const float* __restrict__ lin_l_b,
                                                 const float* __restrict__ lin_r_w, const float* __restrict__ edge_w,
                                                 float* __restrict__ pref, float* __restrict__ av, float* __restrict__ bv) {
    int i = blockIdx.x, t = threadIdx.x;
    __shared__ float xi[D_EMB];
    __shared__ float embL[D_EMB];
    __shared__ float aggL[D_EMB];
    __shared__ int degL;
    int ki = keep[i];            // block-uniform
    if (t < D_EMB) { xi[t] = xn[i * D_EMB + t]; embL[t] = emb[i * D_EMB + t]; aggL[t] = 0.f; }
    if (t == 0) degL = 0;
    __syncthreads();
    if (ki) {
        int nk = knum[0];
        const f32x4* xiv = (const f32x4*)xi;
        for (int u = t; u < nk; u += 256) {
            int j = klist[u];
            if (j == i) continue;
            const f32x4* xj = (const f32x4*)&xn[j * D_EMB];
            f32x4 dv = {0.f, 0.f, 0.f, 0.f};
            #pragma unroll
            for (int d = 0; d < 16; ++d) dv += xiv[d] * xj[d];
            float dot = dv[0] + dv[1] + dv[2] + dv[3];
            if (dot > 0.5f) {
                atomicAdd(&degL, 1);
                #pragma unroll
                for (int d = 0; d < D_EMB; ++d) atomicAdd(&aggL[d], emb[j * D_EMB + d]);
            }
        }
    }
    __syncthreads();
    if (t < D_EMB) {
        float deg = fmaxf((float)degL, 1.0f);
        aggL[t] = ki ? (aggL[t] / deg) : 0.f;    // aggL now holds aggd row
    }
    __syncthreads();
    if (t < P_DIM) {   // wave 0
        float s = lin_l_b[t];
        const float* wl = &lin_l_w[t * D_EMB];
        const float* wr = &lin_r_w[t * D_EMB];
        #pragma unroll
        for (int d = 0; d < D_EMB; ++d) s += aggL[d] * wl[d] + embL[d] * wr[d];
        pref[i * P_DIM + t] = s;
        float a = s * edge_w[t];
        float b = s * edge_w[P_DIM + t];
        #pragma unroll
        for (int off = 16; off; off >>= 1) { a += __shfl_xor(a, off, 64); b += __shfl_xor(b, off, 64); }
        if (t == 0) { av[i] = a; bv[i] = b; }
    }
}

// ---------------- fused pack: blocks 0..2047 = B+cvec ; 2048..4095 = A ----------------
// Bp[nt][kt][r(128)][c^(r&7)] ; Ap[rt(32)][kt][r(64)][c^(r&7)]
__global__ __launch_bounds__(256) void k_pack(const float* __restrict__ comb_w, const float* __restrict__ comb_b,
                                              const int* __restrict__ wk_p, const int* __restrict__ vh_p,
                                              const float* __restrict__ dist, const float* __restrict__ pref,
                                              const float* __restrict__ av, const float* __restrict__ bv,
                                              const float* __restrict__ edge_b,
                                              u16* __restrict__ Bp, u16* __restrict__ Ap,
                                              float* __restrict__ cvec, float* __restrict__ w3) {
    int bid = blockIdx.x, t = threadIdx.x;
    if (bid < 2048) {
        int j = bid;
        int nt = j >> 7, r = j & 127;
        const float* cw = comb_w + (size_t)j * IN_LEN;
        for (int q = t; q < 520; q += 256) {
            int kt = q >> 3, c = q & 7;
            int k0 = q * 8;
            bf16x8 v;
            if (k0 < 4096) {
                f32x4 f0, f1;
                __builtin_memcpy(&f0, cw + 32 + k0, 16);
                __builtin_memcpy(&f1, cw + 36 + k0, 16);
                #pragma unroll
                for (int e = 0; e < 4; ++e) { v[e] = (short)f2bf(f0[e]); v[4 + e] = (short)f2bf(f1[e]); }
            } else if (k0 < 4128) {
                f32x4 f0, f1;
                __builtin_memcpy(&f0, cw + (k0 - 4096), 16);
                __builtin_memcpy(&f1, cw + (k0 - 4092), 16);
                #pragma unroll
                for (int e = 0; e < 4; ++e) { v[e] = (short)f2bf(f0[e]); v[4 + e] = (short)f2bf(f1[e]); }
            } else {
                #pragma unroll
                for (int e = 0; e < 8; ++e) v[e] = 0;
            }
            size_t off = (((size_t)nt * NKT + kt) * 128 + r) * 64 + (size_t)((c ^ (r & 7)) * 8);
            *(bf16x8*)&Bp[off] = v;
        }
        if (t == 0) {
            float wk = (float)wk_p[0], vh = (float)vh_p[0];
            cvec[j] = wk * cw[4128] + vh * cw[4129] + comb_b[j];
            w3[j] = cw[4130];
        }
    } else {
        int row = bid - 2048;
        int rt = row >> 6, r = row & 63;
        float ab = av[row] + edge_b[0];
        const float* drow = dist + (size_t)row * 2048;
        const float* prow = pref + (size_t)row * P_DIM;
        for (int q = t; q < 520; q += 256) {
            int kt = q >> 3, c = q & 7;
            int k0 = q * 8;
            bf16x8 v;
            if (k0 < 2048) {
                const f32x4* bp = (const f32x4*)(bv + k0);
                f32x4 f0 = bp[0], f1 = bp[1];
                #pragma unroll
                for (int e = 0; e < 4; ++e) {
                    float s0 = ab + f0[e]; s0 = (s0 >= 0.f) ? s0 : 0.01f * s0;
                    float s1 = ab + f1[e]; s1 = (s1 >= 0.f) ? s1 : 0.01f * s1;
                    v[e] = (short)f2bf(s0); v[4 + e] = (short)f2bf(s1);
                }
            } else if (k0 < 4096) {
                const f32x4* dp = (const f32x4*)(drow + (k0 - 2048));
                f32x4 f0 = dp[0], f1 = dp[1];
                #pragma unroll
                for (int e = 0; e < 4; ++e) { v[e] = (short)f2bf(f0[e]); v[4 + e] = (short)f2bf(f1[e]); }
            } else if (k0 < 4128) {
                const f32x4* pp = (const f32x4*)(prow + (k0 - 4096));
                f32x4 f0 = pp[0], f1 = pp[1];
                #pragma unroll
                for (int e = 0; e < 4; ++e) { v[e] = (short)f2bf(f0[e]); v[4 + e] = (short)f2bf(f1[e]); }
            } else {
                #pragma unroll
                for (int e = 0; e < 8; ++e) v[e] = 0;
            }
            size_t off = (((size_t)rt * NKT + kt) * 64 + r) * 64 + (size_t)((c ^ (r & 7)) * 8);
            *(bf16x8*)&Ap[off] = v;
        }
    }
}

// ---------------- double-buffered DMA GEMM: 64x128 tile, 1 barrier/kt, drains hidden ----------------
__global__ __launch_bounds__(256) void k_gemm_d(const u16* __restrict__ Ap, const u16* __restrict__ Bp,
                                                float* __restrict__ Cout) {
    __shared__ __attribute__((aligned(16))) short As[2][64 * 64];    // 2 x 8 KB
    __shared__ __attribute__((aligned(16))) short Bs[2][128 * 64];   // 2 x 16 KB
    int t = threadIdx.x;
    int mt = blockIdx.y, nt = blockIdx.x;
    int tileM = mt * 64, tileN = nt * 128;
    int lane = t & 63;
    int wid = t >> 6;
    int waveM = wid & 1, waveN = wid >> 1;
    int l16 = lane & 15, quad = lane >> 4;

    f32x4 acc[2][4];
    #pragma unroll
    for (int a_ = 0; a_ < 2; ++a_)
        #pragma unroll
        for (int b_ = 0; b_ < 4; ++b_) acc[a_][b_] = (f32x4){0.f, 0.f, 0.f, 0.f};

    const u16* ga = Ap + ((size_t)mt * NKT) * 4096 + t * 8;
    const u16* gb = Bp + ((size_t)nt * NKT) * 8192 + t * 8;

    // preload kt=0 into buffer 0
    {
        u16* ad = (u16*)As[0] + t * 8;
        u16* bd = (u16*)Bs[0] + t * 8;
        gload16(ga, ad);
        gload16(ga + 2048, ad + 2048);
        #pragma unroll
        for (int u = 0; u < 4; ++u) gload16(gb + u * 2048, bd + u * 2048);
    }

    int cur = 0;
    for (int kt = 0; kt < NKT; ++kt) {
        __syncthreads();   // drains tile-kt loads (issued a full MFMA phase ago, except kt=0)
        if (kt + 1 < NKT) {
            const u16* gan = ga + (size_t)(kt + 1) * 4096;
            const u16* gbn = gb + (size_t)(kt + 1) * 8192;
            u16* ad = (u16*)As[cur ^ 1] + t * 8;
            u16* bd = (u16*)Bs[cur ^ 1] + t * 8;
            gload16(gan, ad);
            gload16(gan + 2048, ad + 2048);
            #pragma unroll
            for (int u = 0; u < 4; ++u) gload16(gbn + u * 2048, bd + u * 2048);
        }
        const short* Asc = As[cur];
        const short* Bsc = Bs[cur];
        #pragma unroll
        for (int kk = 0; kk < 64; kk += 32) {
            int cbase = kk >> 3;
            bf16x8 af[2], bfr[4];
            #pragma unroll
            for (int mi = 0; mi < 2; ++mi) {
                int row = waveM * 32 + mi * 16 + l16;
                af[mi] = *(const bf16x8*)&Asc[SWZ(row, cbase + quad)];
            }
            #pragma unroll
            for (int ni = 0; ni < 4; ++ni) {
                int row = waveN * 64 + ni * 16 + l16;
                bfr[ni] = *(const bf16x8*)&Bsc[SWZ(row, cbase + quad)];
            }
            #pragma unroll
            for (int mi = 0; mi < 2; ++mi)
                #pragma unroll
                for (int ni = 0; ni < 4; ++ni)
                    acc[mi][ni] = __builtin_amdgcn_mfma_f32_16x16x32_bf16(af[mi], bfr[ni], acc[mi][ni], 0, 0, 0);
        }
        cur ^= 1;
    }
    #pragma unroll
    for (int mi = 0; mi < 2; ++mi)
        #pragma unroll
        for (int ni = 0; ni < 4; ++ni) {
            int row = tileM + waveM * 32 + mi * 16 + quad * 4;
            int col = tileN + waveN * 64 + ni * 16 + l16;
            float* cp = Cout + (size_t)row * N_NODES + col;
            #pragma unroll
            for (int rr = 0; rr < 4; ++rr) cp[(size_t)rr * N_NODES] = acc[mi][ni][rr];
        }
}

// ---------------- epilogue: + cvec + keep_i*w3, log-softmax (f32x4, in place) ----------------
__global__ __launch_bounds__(256) void k_epi(const float* __restrict__ cvec, const float* __restrict__ w3,
                                             const int* __restrict__ keep, float* __restrict__ out) {
    int i = blockIdx.x, t = threadIdx.x;
    __shared__ float redmax[4], redsum[4];
    float ki = keep[i] ? 1.f : 0.f;
    f32x4* orow = (f32x4*)(out + (size_t)i * N_NODES);
    const f32x4* cv = (const f32x4*)cvec;
    const f32x4* wv = (const f32x4*)w3;
    f32x4 v0 = orow[t] + cv[t] + ki * wv[t];
    f32x4 v1 = orow[t + 256] + cv[t + 256] + ki * wv[t + 256];
    float vmax = fmaxf(fmaxf(fmaxf(v0[0], v0[1]), fmaxf(v0[2], v0[3])),
                       fmaxf(fmaxf(v1[0], v1[1]), fmaxf(v1[2], v1[3])));
    #pragma unroll
    for (int off = 32; off; off >>= 1) vmax = fmaxf(vmax, __shfl_xor(vmax, off, 64));
    if ((t & 63) == 0) redmax[t >> 6] = vmax;
    __syncthreads();
    vmax = fmaxf(fmaxf(redmax[0], redmax[1]), fmaxf(redmax[2], redmax[3]));
    float se = 0.f;
    #pragma unroll
    for (int e = 0; e < 4; ++e) se += expf(v0[e] - vmax) + expf(v1[e] - vmax);
    #pragma unroll
    for (int off = 32; off; off >>= 1) se += __shfl_xor(se, off, 64);
    if ((t & 63) == 0) redsum[t >> 6] = se;
    __syncthreads();
    se = redsum[0] + redsum[1] + redsum[2] + redsum[3];
    float lz = vmax + logf(se);
    orow[t] = v0 - lz;
    orow[t + 256] = v1 - lz;
}

extern "C" void kernel_launch(void* const* d_in, const int* in_sizes, int n_in,
                              void* d_out, int out_size, void* d_ws, size_t ws_size,
                              hipStream_t stream) {
    const float* dist    = (const float*)d_in[0];
    const float* emb     = (const float*)d_in[1];
    const float* lin_l_w = (const float*)d_in[2];
    const float* lin_l_b = (const float*)d_in[3];
    const float* lin_r_w = (const float*)d_in[4];
    const float* edge_w  = (const float*)d_in[5];
    const float* edge_b  = (const float*)d_in[6];
    const float* comb_w  = (const float*)d_in[7];
    const float* comb_b  = (const float*)d_in[8];
    const int* stops     = (const int*)d_in[9];
    const int* wk        = (const int*)d_in[10];
    const int* vh        = (const int*)d_in[11];

    // ws layout (<= 34.93 MB, confirmed budget >= 35.43 MB)
    char* ws = (char*)d_ws;
    float* xn    = (float*)(ws + 0);          // 524288
    int*   keep  = (int*)(ws + 524288);       // 8192
    float* pref  = (float*)(ws + 532480);     // 262144
    float* av    = (float*)(ws + 794624);     // 8192
    float* bv    = (float*)(ws + 802816);     // 8192
    float* cvec  = (float*)(ws + 811008);     // 8192
    float* w3    = (float*)(ws + 819200);     // 8192
    int*   klist = (int*)(ws + 827392);       // 8192
    int*   knum  = (int*)(ws + 835584);       // 64
    u16*   Ap    = (u16*)(ws + 843776);       // 17039360 -> 17883136
    u16*   Bp    = (u16*)(ws + 17883136);     // 17039360 -> 34922496
    float* out   = (float*)d_out;             // f32 [2048,2048]

    hipLaunchKernelGGL(k_prep,    dim3(513),      dim3(256), 0, stream, emb, stops, xn, keep, klist, knum);
    hipLaunchKernelGGL(k_aggpref, dim3(2048),     dim3(256), 0, stream, xn, emb, keep, klist, knum,
                       lin_l_w, lin_l_b, lin_r_w, edge_w, pref, av, bv);
    hipLaunchKernelGGL(k_pack,    dim3(4096),     dim3(256), 0, stream, comb_w, comb_b, wk, vh,
                       dist, pref, av, bv, edge_b, Bp, Ap, cvec, w3);
    hipLaunchKernelGGL(k_gemm_d,  dim3(16, 32),   dim3(256), 0, stream, Ap, Bp, out);
    hipLaunchKernelGGL(k_epi,     dim3(2048),     dim3(256), 0, stream, cvec, w3, keep, out);
}

// Round 13
// 196.330 us; speedup vs baseline: 1.2515x; 1.0013x over previous
//
#include <hip/hip_runtime.h>

typedef unsigned short u16;
typedef __attribute__((ext_vector_type(8))) short bf16x8;
typedef __attribute__((ext_vector_type(4))) float f32x4;

// round-to-nearest (ties away): 2 VALU ops
__device__ __forceinline__ u16 f2bf(float f) {
    return (u16)((__float_as_uint(f) + 0x8000u) >> 16);
}

#define N_NODES 2048
#define D_EMB 64
#define P_DIM 32
#define NS_STOPS 512
#define IN_LEN 4131   // 32 + 2048 + 2048 + 3
#define NKT 65        // K-tiles of 64 (2048 es + 2048 dist + 32 pref + 32 pad)

// 16B-chunk XOR swizzle within a tile row (8 chunks of 8 shorts)
#define SWZ(row, c) ((((row) * 8) + ((c) ^ ((row) & 7))) * 8)

__device__ __forceinline__ void gload16(const u16* g, u16* l) {
    __builtin_amdgcn_global_load_lds((const __attribute__((address_space(1))) void*)g,
                                     (__attribute__((address_space(3))) void*)l, 16, 0, 0);
}

// ---------------- fused: stops bitmap + cosine graph + mean agg + pref + a,b (self-contained) ----------------
__global__ __launch_bounds__(256) void k_aggpref(const float* __restrict__ emb, const int* __restrict__ stops,
                                                 const float* __restrict__ lin_l_w, const float* __restrict__ lin_l_b,
                                                 const float* __restrict__ lin_r_w, const float* __restrict__ edge_w,
                                                 float* __restrict__ pref, float* __restrict__ av, float* __restrict__ bv) {
    int i = blockIdx.x, t = threadIdx.x;
    __shared__ int bm[64];          // 2048-bit stop bitmap
    __shared__ int kl[NS_STOPS];
    __shared__ int cnt, degL;
    __shared__ float xi[D_EMB];     // raw emb row i
    __shared__ float aggL[D_EMB];
    __shared__ float niS;
    if (t < 64) bm[t] = 0;
    if (t == 0) { cnt = 0; degL = 0; }
    if (t < D_EMB) { xi[t] = emb[i * D_EMB + t]; aggL[t] = 0.f; }
    __syncthreads();
    {   // scatter stops into bitmap
        int s0 = stops[t], s1 = stops[t + 256];
        atomicOr(&bm[s0 >> 5], 1 << (s0 & 31));
        atomicOr(&bm[s1 >> 5], 1 << (s1 & 31));
    }
    __syncthreads();
    {   // compact set nodes into kl
        int w = bm[t >> 2];          // thread t covers bits (t&3)*8 .. +7 of word t>>2
        int base = (t >> 2) * 32 + (t & 3) * 8;
        #pragma unroll
        for (int e = 0; e < 8; ++e)
            if ((w >> ((t & 3) * 8 + e)) & 1) { int p = atomicAdd(&cnt, 1); kl[p] = base + e; }
    }
    // norm of row i (wave 0)
    if (t < 64) {
        float s = xi[t] * xi[t];
        #pragma unroll
        for (int off = 32; off; off >>= 1) s += __shfl_xor(s, off, 64);
        if (t == 0) niS = fmaxf(sqrtf(s), 1e-8f);
    }
    __syncthreads();
    int ki = (bm[i >> 5] >> (i & 31)) & 1;   // block-uniform
    if (ki) {
        int nk = cnt;
        float ni = niS;
        const f32x4* xiv = (const f32x4*)xi;
        for (int u = t; u < nk; u += 256) {
            int j = kl[u];
            if (j == i) continue;
            const f32x4* ej = (const f32x4*)&emb[j * D_EMB];
            f32x4 er[16];
            f32x4 dv = {0.f, 0.f, 0.f, 0.f};
            f32x4 sv = {0.f, 0.f, 0.f, 0.f};
            #pragma unroll
            for (int d = 0; d < 16; ++d) {
                er[d] = ej[d];
                dv += xiv[d] * er[d];
                sv += er[d] * er[d];
            }
            float dot = dv[0] + dv[1] + dv[2] + dv[3];
            float nj = fmaxf(sqrtf(sv[0] + sv[1] + sv[2] + sv[3]), 1e-8f);
            if (dot > 0.5f * ni * nj) {
                atomicAdd(&degL, 1);
                #pragma unroll
                for (int d = 0; d < 16; ++d) {
                    atomicAdd(&aggL[d * 4 + 0], er[d][0]);
                    atomicAdd(&aggL[d * 4 + 1], er[d][1]);
                    atomicAdd(&aggL[d * 4 + 2], er[d][2]);
                    atomicAdd(&aggL[d * 4 + 3], er[d][3]);
                }
            }
        }
    }
    __syncthreads();
    if (t < D_EMB) {
        float deg = fmaxf((float)degL, 1.0f);
        aggL[t] = ki ? (aggL[t] / deg) : 0.f;    // aggL now holds aggd row
    }
    __syncthreads();
    if (t < P_DIM) {   // wave 0
        float s = lin_l_b[t];
        const float* wl = &lin_l_w[t * D_EMB];
        const float* wr = &lin_r_w[t * D_EMB];
        #pragma unroll
        for (int d = 0; d < D_EMB; ++d) s += aggL[d] * wl[d] + xi[d] * wr[d];
        pref[i * P_DIM + t] = s;
        float a = s * edge_w[t];
        float b = s * edge_w[P_DIM + t];
        #pragma unroll
        for (int off = 16; off; off >>= 1) { a += __shfl_xor(a, off, 64); b += __shfl_xor(b, off, 64); }
        if (t == 0) { av[i] = a; bv[i] = b; }
    }
}

// ---------------- fused pack: blocks 0..2047 = B+cvec ; 2048..4095 = A ----------------
// Bp[nt][kt][r(128)][c^(r&7)] ; Ap[rt(32)][kt][r(64)][c^(r&7)]
__global__ __launch_bounds__(256) void k_pack(const float* __restrict__ comb_w, const float* __restrict__ comb_b,
                                              const int* __restrict__ wk_p, const int* __restrict__ vh_p,
                                              const float* __restrict__ dist, const float* __restrict__ pref,
                                              const float* __restrict__ av, const float* __restrict__ bv,
                                              const float* __restrict__ edge_b,
                                              u16* __restrict__ Bp, u16* __restrict__ Ap,
                                              float* __restrict__ cvec, float* __restrict__ w3) {
    int bid = blockIdx.x, t = threadIdx.x;
    if (bid < 2048) {
        int j = bid;
        int nt = j >> 7, r = j & 127;
        const float* cw = comb_w + (size_t)j * IN_LEN;
        for (int q = t; q < 520; q += 256) {
            int kt = q >> 3, c = q & 7;
            int k0 = q * 8;
            bf16x8 v;
            if (k0 < 4096) {
                f32x4 f0, f1;
                __builtin_memcpy(&f0, cw + 32 + k0, 16);
                __builtin_memcpy(&f1, cw + 36 + k0, 16);
                #pragma unroll
                for (int e = 0; e < 4; ++e) { v[e] = (short)f2bf(f0[e]); v[4 + e] = (short)f2bf(f1[e]); }
            } else if (k0 < 4128) {
                f32x4 f0, f1;
                __builtin_memcpy(&f0, cw + (k0 - 4096), 16);
                __builtin_memcpy(&f1, cw + (k0 - 4092), 16);
                #pragma unroll
                for (int e = 0; e < 4; ++e) { v[e] = (short)f2bf(f0[e]); v[4 + e] = (short)f2bf(f1[e]); }
            } else {
                #pragma unroll
                for (int e = 0; e < 8; ++e) v[e] = 0;
            }
            size_t off = (((size_t)nt * NKT + kt) * 128 + r) * 64 + (size_t)((c ^ (r & 7)) * 8);
            *(bf16x8*)&Bp[off] = v;
        }
        if (t == 0) {
            float wk = (float)wk_p[0], vh = (float)vh_p[0];
            cvec[j] = wk * cw[4128] + vh * cw[4129] + comb_b[j];
            w3[j] = cw[4130];
        }
    } else {
        int row = bid - 2048;
        int rt = row >> 6, r = row & 63;
        float ab = av[row] + edge_b[0];
        const float* drow = dist + (size_t)row * 2048;
        const float* prow = pref + (size_t)row * P_DIM;
        for (int q = t; q < 520; q += 256) {
            int kt = q >> 3, c = q & 7;
            int k0 = q * 8;
            bf16x8 v;
            if (k0 < 2048) {
                const f32x4* bp = (const f32x4*)(bv + k0);
                f32x4 f0 = bp[0], f1 = bp[1];
                #pragma unroll
                for (int e = 0; e < 4; ++e) {
                    float s0 = ab + f0[e]; s0 = (s0 >= 0.f) ? s0 : 0.01f * s0;
                    float s1 = ab + f1[e]; s1 = (s1 >= 0.f) ? s1 : 0.01f * s1;
                    v[e] = (short)f2bf(s0); v[4 + e] = (short)f2bf(s1);
                }
            } else if (k0 < 4096) {
                const f32x4* dp = (const f32x4*)(drow + (k0 - 2048));
                f32x4 f0 = dp[0], f1 = dp[1];
                #pragma unroll
                for (int e = 0; e < 4; ++e) { v[e] = (short)f2bf(f0[e]); v[4 + e] = (short)f2bf(f1[e]); }
            } else if (k0 < 4128) {
                const f32x4* pp = (const f32x4*)(prow + (k0 - 4096));
                f32x4 f0 = pp[0], f1 = pp[1];
                #pragma unroll
                for (int e = 0; e < 4; ++e) { v[e] = (short)f2bf(f0[e]); v[4 + e] = (short)f2bf(f1[e]); }
            } else {
                #pragma unroll
                for (int e = 0; e < 8; ++e) v[e] = 0;
            }
            size_t off = (((size_t)rt * NKT + kt) * 64 + r) * 64 + (size_t)((c ^ (r & 7)) * 8);
            *(bf16x8*)&Ap[off] = v;
        }
    }
}

// ---------------- double-buffered DMA GEMM: 64x128 tile, 1 barrier/kt ----------------
__global__ __launch_bounds__(256) void k_gemm_d(const u16* __restrict__ Ap, const u16* __restrict__ Bp,
                                                float* __restrict__ Cout) {
    __shared__ __attribute__((aligned(16))) short As[2][64 * 64];    // 2 x 8 KB
    __shared__ __attribute__((aligned(16))) short Bs[2][128 * 64];   // 2 x 16 KB
    int t = threadIdx.x;
    int mt = blockIdx.y, nt = blockIdx.x;
    int tileM = mt * 64, tileN = nt * 128;
    int lane = t & 63;
    int wid = t >> 6;
    int waveM = wid & 1, waveN = wid >> 1;
    int l16 = lane & 15, quad = lane >> 4;

    f32x4 acc[2][4];
    #pragma unroll
    for (int a_ = 0; a_ < 2; ++a_)
        #pragma unroll
        for (int b_ = 0; b_ < 4; ++b_) acc[a_][b_] = (f32x4){0.f, 0.f, 0.f, 0.f};

    const u16* ga = Ap + ((size_t)mt * NKT) * 4096 + t * 8;
    const u16* gb = Bp + ((size_t)nt * NKT) * 8192 + t * 8;

    // preload kt=0 into buffer 0
    {
        u16* ad = (u16*)As[0] + t * 8;
        u16* bd = (u16*)Bs[0] + t * 8;
        gload16(ga, ad);
        gload16(ga + 2048, ad + 2048);
        #pragma unroll
        for (int u = 0; u < 4; ++u) gload16(gb + u * 2048, bd + u * 2048);
    }

    int cur = 0;
    for (int kt = 0; kt < NKT; ++kt) {
        __syncthreads();   // drains tile-kt loads (issued a full MFMA phase ago, except kt=0)
        if (kt + 1 < NKT) {
            const u16* gan = ga + (size_t)(kt + 1) * 4096;
            const u16* gbn = gb + (size_t)(kt + 1) * 8192;
            u16* ad = (u16*)As[cur ^ 1] + t * 8;
            u16* bd = (u16*)Bs[cur ^ 1] + t * 8;
            gload16(gan, ad);
            gload16(gan + 2048, ad + 2048);
            #pragma unroll
            for (int u = 0; u < 4; ++u) gload16(gbn + u * 2048, bd + u * 2048);
        }
        const short* Asc = As[cur];
        const short* Bsc = Bs[cur];
        #pragma unroll
        for (int kk = 0; kk < 64; kk += 32) {
            int cbase = kk >> 3;
            bf16x8 af[2], bfr[4];
            #pragma unroll
            for (int mi = 0; mi < 2; ++mi) {
                int row = waveM * 32 + mi * 16 + l16;
                af[mi] = *(const bf16x8*)&Asc[SWZ(row, cbase + quad)];
            }
            #pragma unroll
            for (int ni = 0; ni < 4; ++ni) {
                int row = waveN * 64 + ni * 16 + l16;
                bfr[ni] = *(const bf16x8*)&Bsc[SWZ(row, cbase + quad)];
            }
            #pragma unroll
            for (int mi = 0; mi < 2; ++mi)
                #pragma unroll
                for (int ni = 0; ni < 4; ++ni)
                    acc[mi][ni] = __builtin_amdgcn_mfma_f32_16x16x32_bf16(af[mi], bfr[ni], acc[mi][ni], 0, 0, 0);
        }
        cur ^= 1;
    }
    #pragma unroll
    for (int mi = 0; mi < 2; ++mi)
        #pragma unroll
        for (int ni = 0; ni < 4; ++ni) {
            int row = tileM + waveM * 32 + mi * 16 + quad * 4;
            int col = tileN + waveN * 64 + ni * 16 + l16;
            float* cp = Cout + (size_t)row * N_NODES + col;
            #pragma unroll
            for (int rr = 0; rr < 4; ++rr) cp[(size_t)rr * N_NODES] = acc[mi][ni][rr];
        }
}

// ---------------- epilogue: + cvec + keep_i*w3, log-softmax (f32x4, in place, inline keep) ----------------
__global__ __launch_bounds__(256) void k_epi(const float* __restrict__ cvec, const float* __restrict__ w3,
                                             const int* __restrict__ stops, float* __restrict__ out) {
    int i = blockIdx.x, t = threadIdx.x;
    __shared__ int bm[64];
    __shared__ float redmax[4], redsum[4];
    if (t < 64) bm[t] = 0;
    __syncthreads();
    {
        int s0 = stops[t], s1 = stops[t + 256];
        atomicOr(&bm[s0 >> 5], 1 << (s0 & 31));
        atomicOr(&bm[s1 >> 5], 1 << (s1 & 31));
    }
    __syncthreads();
    float ki = (float)((bm[i >> 5] >> (i & 31)) & 1);
    f32x4* orow = (f32x4*)(out + (size_t)i * N_NODES);
    const f32x4* cv = (const f32x4*)cvec;
    const f32x4* wv = (const f32x4*)w3;
    f32x4 v0 = orow[t] + cv[t] + ki * wv[t];
    f32x4 v1 = orow[t + 256] + cv[t + 256] + ki * wv[t + 256];
    float vmax = fmaxf(fmaxf(fmaxf(v0[0], v0[1]), fmaxf(v0[2], v0[3])),
                       fmaxf(fmaxf(v1[0], v1[1]), fmaxf(v1[2], v1[3])));
    #pragma unroll
    for (int off = 32; off; off >>= 1) vmax = fmaxf(vmax, __shfl_xor(vmax, off, 64));
    if ((t & 63) == 0) redmax[t >> 6] = vmax;
    __syncthreads();
    vmax = fmaxf(fmaxf(redmax[0], redmax[1]), fmaxf(redmax[2], redmax[3]));
    float se = 0.f;
    #pragma unroll
    for (int e = 0; e < 4; ++e) se += expf(v0[e] - vmax) + expf(v1[e] - vmax);
    #pragma unroll
    for (int off = 32; off; off >>= 1) se += __shfl_xor(se, off, 64);
    if ((t & 63) == 0) redsum[t >> 6] = se;
    __syncthreads();
    se = redsum[0] + redsum[1] + redsum[2] + redsum[3];
    float lz = vmax + logf(se);
    orow[t] = v0 - lz;
    orow[t + 256] = v1 - lz;
}

extern "C" void kernel_launch(void* const* d_in, const int* in_sizes, int n_in,
                              void* d_out, int out_size, void* d_ws, size_t ws_size,
                              hipStream_t stream) {
    const float* dist    = (const float*)d_in[0];
    const float* emb     = (const float*)d_in[1];
    const float* lin_l_w = (const float*)d_in[2];
    const float* lin_l_b = (const float*)d_in[3];
    const float* lin_r_w = (const float*)d_in[4];
    const float* edge_w  = (const float*)d_in[5];
    const float* edge_b  = (const float*)d_in[6];
    const float* comb_w  = (const float*)d_in[7];
    const float* comb_b  = (const float*)d_in[8];
    const int* stops     = (const int*)d_in[9];
    const int* wk        = (const int*)d_in[10];
    const int* vh        = (const int*)d_in[11];

    // ws layout: 34.37 MB (confirmed budget >= 35.43 MB from round 10)
    char* ws = (char*)d_ws;
    float* pref  = (float*)(ws + 0);          // 262144
    float* av    = (float*)(ws + 262144);     // 8192
    float* bv    = (float*)(ws + 270336);     // 8192
    float* cvec  = (float*)(ws + 278528);     // 8192
    float* w3    = (float*)(ws + 286720);     // 8192
    u16*   Ap    = (u16*)(ws + 294912);       // 17039360 -> 17334272
    u16*   Bp    = (u16*)(ws + 17334272);     // 17039360 -> 34373632
    float* out   = (float*)d_out;             // f32 [2048,2048]

    hipLaunchKernelGGL(k_aggpref, dim3(2048),   dim3(256), 0, stream, emb, stops,
                       lin_l_w, lin_l_b, lin_r_w, edge_w, pref, av, bv);
    hipLaunchKernelGGL(k_pack,    dim3(4096),   dim3(256), 0, stream, comb_w, comb_b, wk, vh,
                       dist, pref, av, bv, edge_b, Bp, Ap, cvec, w3);
    hipLaunchKernelGGL(k_gemm_d,  dim3(16, 32), dim3(256), 0, stream, Ap, Bp, out);
    hipLaunchKernelGGL(k_epi,     dim3(2048),   dim3(256), 0, stream, cvec, w3, stops, out);
}